// Round 8
// baseline (111.608 us; speedup 1.0000x reference)
//
#include <hip/hip_runtime.h>
#include <math.h>

#define BB 512
#define DD 128
#define KK 8
#define BOUNDARY 4
#define POISON 0xAAAAAAAAu

// ---------------- workspace layout (bytes) ----------------
// accumS : 0  .. 4    (float)    device-wide loss sum
// accumC : 4  .. 8    (int)      device-wide hinge count
// done   : 8  .. 12   (unsigned) completed-block counter
// ws is re-poisoned to 0xAA before every launch; each cell is initialized
// exactly once per launch via atomicCAS(poison -> 0): every block issues the
// CAS before its add on the same address (program order on one address), so
// the device-wide first op on each cell is a successful CAS. Running values
// (nonneg float sums / counts <= ~4k / done <= 512) can never equal the
// poison bit pattern, so late CASes always fail harmlessly.
//
// Algebraic facts exploited (boundary = int(512/128) = 4):
//  * anchor rows belong to classes with <= 3 members, so the positive top-8
//    selects ALL same-class rows: mask_ap[i][j] == anchors[i] & tgt[j]==tgt[i] & i!=j.
//  * block k owns column k: its neg top-8 rows r are exactly the (i=r, k)
//    entries of mask_an, and d[r,k] is the value the block just computed.
//  * the <= 16 positive distances d[r,j] per block are recomputed directly
//    from x (one 128-dim dot each) — they feed only hinge values, not
//    selections, so accumulation-order ulps are harmless.

__global__ __launch_bounds__(256) void fused_kernel(
    const float* __restrict__ x, const int* __restrict__ tgt,
    float* __restrict__ accumS, int* __restrict__ accumC,
    unsigned* __restrict__ done, float* __restrict__ out)
{
    __shared__ float4 xi4[DD / 4];
    __shared__ float s_d[BB];          // raw distances, column k (== row k)
    __shared__ float s_vn[BB];         // -d masked to -inf on same-class
    __shared__ float s_sq[BB];         // squared norms of all rows
    __shared__ int   s_tgt[BB];
    __shared__ int   s_cnt[128];       // class histogram
    __shared__ int   s_sel[KK];        // selected neg rows, -1 invalid
    __shared__ int   s_pr[16], s_pj[16];
    __shared__ int   s_np;

    int k = blockIdx.x;
    int t = threadIdx.x;
    if (t < DD / 4) xi4[t] = ((const float4*)(x + k * DD))[t];
    if (t < 128) s_cnt[t] = 0;
    if (t == 0) s_np = 0;
    s_tgt[t]       = tgt[t];
    s_tgt[t + 256] = tgt[t + 256];
    __syncthreads();
    int tk = s_tgt[k];

    // sqk with the same 4-chain structure as sqr below -> diagonal exactly 0
    float q0 = 0.f, q1 = 0.f, q2 = 0.f, q3 = 0.f;
    for (int c = 0; c < DD / 4; ++c) {
        float4 a = xi4[c];
        q0 += a.x * a.x; q1 += a.y * a.y; q2 += a.z * a.z; q3 += a.w * a.w;
    }
    float sqk = (q0 + q1) + (q2 + q3);

    for (int rr = 0; rr < 2; ++rr) {
        int r = t + rr * 256;
        const float4* xr = (const float4*)(x + r * DD);
        float d0 = 0.f, d1 = 0.f, d2 = 0.f, d3 = 0.f;
        float s0 = 0.f, s1 = 0.f, s2 = 0.f, s3 = 0.f;
        for (int c = 0; c < DD / 4; ++c) {
            float4 a = xi4[c], b = xr[c];
            d0 += a.x * b.x; d1 += a.y * b.y; d2 += a.z * b.z; d3 += a.w * b.w;
            s0 += b.x * b.x; s1 += b.y * b.y; s2 += b.z * b.z; s3 += b.w * b.w;
        }
        float dot = (d0 + d1) + (d2 + d3);
        float sqr = (s0 + s1) + (s2 + s3);
        float dsq = fmaxf((sqk + sqr) - 2.f * dot, 0.f);
        float dv = (dsq == 0.f) ? 0.f : sqrtf(dsq);
        s_d[r]  = dv;
        s_sq[r] = sqr;
        s_vn[r] = (s_tgt[r] == tk) ? -INFINITY : -dv;
    }
    __syncthreads();

    int wave = t >> 6, lane = t & 63;
    if (wave == 0) {
        // neg top-8: largest -d among different-class rows (lax.top_k order:
        // descending value, lower index on tie) — byte-identical to round 7
        float v[8];
        for (int q = 0; q < 8; ++q) v[q] = s_vn[q * 64 + lane];
        for (int pass = 0; pass < KK; ++pass) {
            float bv = -INFINITY; int bq = -1;
            for (int q = 0; q < 8; ++q)
                if (v[q] > bv) { bv = v[q]; bq = q; }   // strict > keeps lowest q
            int bi = (bq >= 0) ? (bq * 64 + lane) : (1 << 30);
            for (int off = 32; off > 0; off >>= 1) {
                float ov = __shfl_down(bv, off);
                int   oi = __shfl_down(bi, off);
                if (ov > bv || (ov == bv && oi < bi)) { bv = ov; bi = oi; }
            }
            bv = __shfl(bv, 0); bi = __shfl(bi, 0);
            if (lane == 0) s_sel[pass] = (bv == -INFINITY) ? -1 : bi;
            if ((bi & 63) == lane) v[bi >> 6] = -INFINITY;
        }
    } else if (wave == 1) {
        // class histogram (includes self-counts)
        for (int q = 0; q < 8; ++q) atomicAdd(&s_cnt[s_tgt[q * 64 + lane]], 1);
    }
    __syncthreads();

    // collect (anchor r, positive j) pairs: 8 groups of 32 threads, one per slot
    {
        int p = t >> 5, l = t & 31;
        int r = s_sel[p];
        if (r >= 0) {
            int tr = s_tgt[r];
            if (s_cnt[tr] < BOUNDARY) {          // anchor: class size <= 3
                for (int j = l; j < BB; j += 32)
                    if (j != r && s_tgt[j] == tr) {
                        int idx = atomicAdd(&s_np, 1);
                        s_pr[idx] = r; s_pj[idx] = j;
                    }
            }
        }
    }
    __syncthreads();

    // hinge terms: <= 16 pairs, all resident in wave 0
    float s = 0.f; int c = 0;
    if (t < s_np) {
        int r = s_pr[t], j = s_pj[t];
        const float4* xr = (const float4*)(x + r * DD);
        const float4* xj = (const float4*)(x + j * DD);
        float d0 = 0.f, d1 = 0.f, d2 = 0.f, d3 = 0.f;
        for (int cc = 0; cc < DD / 4; ++cc) {
            float4 a = xr[cc], b = xj[cc];
            d0 += a.x * b.x; d1 += a.y * b.y; d2 += a.z * b.z; d3 += a.w * b.w;
        }
        float dot = (d0 + d1) + (d2 + d3);
        float dsq = fmaxf((s_sq[r] + s_sq[j]) - 2.f * dot, 0.f);
        float dpos = (dsq == 0.f) ? 0.f : sqrtf(dsq);
        float tv = dpos - s_d[r] + 1.0f;         // d[r,j] - d[r,k] + margin
        if (tv > 0.f) { s = tv; c = (tv > 1e-7f) ? 1 : 0; }
    }
    if (wave == 0) {
        for (int off = 32; off > 0; off >>= 1) {
            s += __shfl_down(s, off);
            c += __shfl_down(c, off);
        }
        if (lane == 0) {
            // init-from-poison (exactly one CAS succeeds device-wide per cell)
            atomicCAS((unsigned*)accumS, POISON, 0u);
            atomicCAS((unsigned*)accumC, POISON, 0u);
            if (s != 0.f) atomicAdd(accumS, s);
            if (c != 0)   atomicAdd(accumC, c);
            __threadfence();                     // release our adds
            atomicCAS(done, POISON, 0u);
            unsigned prev = atomicAdd(done, 1u);
            if (prev == BB - 1) {                // last block: all adds ordered before
                __threadfence();                 // acquire
                float S = atomicAdd(accumS, 0.f);   // coherent atomic reads
                int   C = atomicAdd(accumC, 0);
                out[0] = S / ((float)C + 1e-7f);
            }
        }
    }
}

extern "C" void kernel_launch(void* const* d_in, const int* in_sizes, int n_in,
                              void* d_out, int out_size, void* d_ws, size_t ws_size,
                              hipStream_t stream) {
    const float* x   = (const float*)d_in[0];
    const int*   tgt = (const int*)d_in[1];
    float* out = (float*)d_out;

    char* ws = (char*)d_ws;
    float*    accumS = (float*)(ws + 0);
    int*      accumC = (int*)(ws + 4);
    unsigned* done   = (unsigned*)(ws + 8);

    fused_kernel<<<BB, 256, 0, stream>>>(x, tgt, accumS, accumC, done, out);
}

// Round 9
// 90.135 us; speedup vs baseline: 1.2382x; 1.2382x over previous
//
#include <hip/hip_runtime.h>
#include <math.h>

#define BB 512
#define DD 128
#define KK 8
#define BOUNDARY 4
#define POISON 0xAAAAAAAAu
#define NSHARD 64                      // 8 blocks per shard
#define CELL_STRIDE 128                // one cell per 128-B line

// ---------------- workspace layout (bytes) ----------------
// cells : 0    .. 8192   (64 cells x 128 B: [0]=float S, [4]=int C, [8]=u32 doneShard)
// done2 : 8192 .. 8196   (unsigned, counts completed shards)
// ws is re-poisoned 0xAA before every launch. Each cell field is initialized
// once per launch via atomicCAS(poison -> 0) issued by every toucher before
// its first add on that address (program order per address => the first op
// device-wide is a successful CAS). Running values (nonneg float sums, small
// counts, counters <= 512) never equal the poison pattern, so late CASes fail
// harmlessly. Contention per address: <= 8 blocks (cells), <= 64 (done2) —
// the round-8 lesson: 512-way same-address device atomics cost ~50 us.
//
// Algebraic facts exploited (boundary = int(512/128) = 4):
//  * anchor rows belong to classes with <= 3 members, so the positive top-8
//    selects ALL same-class rows: mask_ap[i][j] == anchors[i] & tgt[j]==tgt[i] & i!=j.
//  * block k owns column k: its neg top-8 rows r are exactly the (i=r, k)
//    entries of mask_an, and d[r,k] is the value the block just computed.
//  * the <= 16 positive distances d[r,j] per block are recomputed directly
//    from x (one 128-dim dot each) — hinge values only, not selections.

__global__ __launch_bounds__(256) void fused_kernel(
    const float* __restrict__ x, const int* __restrict__ tgt,
    char* __restrict__ cells, unsigned* __restrict__ done2,
    float* __restrict__ out)
{
    __shared__ float4 xi4[DD / 4];
    __shared__ float s_d[BB];          // raw distances, column k (== row k)
    __shared__ float s_vn[BB];         // -d masked to -inf on same-class
    __shared__ float s_sq[BB];         // squared norms of all rows
    __shared__ int   s_tgt[BB];
    __shared__ int   s_cnt[128];       // class histogram
    __shared__ int   s_sel[KK];        // selected neg rows, -1 invalid
    __shared__ int   s_pr[16], s_pj[16];
    __shared__ int   s_np;

    int k = blockIdx.x;
    int t = threadIdx.x;
    if (t < DD / 4) xi4[t] = ((const float4*)(x + k * DD))[t];
    if (t < 128) s_cnt[t] = 0;
    if (t == 0) s_np = 0;
    s_tgt[t]       = tgt[t];
    s_tgt[t + 256] = tgt[t + 256];
    __syncthreads();
    int tk = s_tgt[k];

    // sqk with the same 4-chain structure as sqr below -> diagonal exactly 0
    float q0 = 0.f, q1 = 0.f, q2 = 0.f, q3 = 0.f;
    for (int c = 0; c < DD / 4; ++c) {
        float4 a = xi4[c];
        q0 += a.x * a.x; q1 += a.y * a.y; q2 += a.z * a.z; q3 += a.w * a.w;
    }
    float sqk = (q0 + q1) + (q2 + q3);

    for (int rr = 0; rr < 2; ++rr) {
        int r = t + rr * 256;
        const float4* xr = (const float4*)(x + r * DD);
        float d0 = 0.f, d1 = 0.f, d2 = 0.f, d3 = 0.f;
        float s0 = 0.f, s1 = 0.f, s2 = 0.f, s3 = 0.f;
        for (int c = 0; c < DD / 4; ++c) {
            float4 a = xi4[c], b = xr[c];
            d0 += a.x * b.x; d1 += a.y * b.y; d2 += a.z * b.z; d3 += a.w * b.w;
            s0 += b.x * b.x; s1 += b.y * b.y; s2 += b.z * b.z; s3 += b.w * b.w;
        }
        float dot = (d0 + d1) + (d2 + d3);
        float sqr = (s0 + s1) + (s2 + s3);
        float dsq = fmaxf((sqk + sqr) - 2.f * dot, 0.f);
        float dv = (dsq == 0.f) ? 0.f : sqrtf(dsq);
        s_d[r]  = dv;
        s_sq[r] = sqr;
        s_vn[r] = (s_tgt[r] == tk) ? -INFINITY : -dv;
    }
    __syncthreads();

    int wave = t >> 6, lane = t & 63;
    if (wave == 0) {
        // neg top-8: largest -d among different-class rows (lax.top_k order:
        // descending value, lower index on tie) — byte-identical to round 7
        float v[8];
        for (int q = 0; q < 8; ++q) v[q] = s_vn[q * 64 + lane];
        for (int pass = 0; pass < KK; ++pass) {
            float bv = -INFINITY; int bq = -1;
            for (int q = 0; q < 8; ++q)
                if (v[q] > bv) { bv = v[q]; bq = q; }   // strict > keeps lowest q
            int bi = (bq >= 0) ? (bq * 64 + lane) : (1 << 30);
            for (int off = 32; off > 0; off >>= 1) {
                float ov = __shfl_down(bv, off);
                int   oi = __shfl_down(bi, off);
                if (ov > bv || (ov == bv && oi < bi)) { bv = ov; bi = oi; }
            }
            bv = __shfl(bv, 0); bi = __shfl(bi, 0);
            if (lane == 0) s_sel[pass] = (bv == -INFINITY) ? -1 : bi;
            if ((bi & 63) == lane) v[bi >> 6] = -INFINITY;
        }
    } else if (wave == 1) {
        // class histogram (includes self-counts)
        for (int q = 0; q < 8; ++q) atomicAdd(&s_cnt[s_tgt[q * 64 + lane]], 1);
    }
    __syncthreads();

    // collect (anchor r, positive j) pairs: 8 groups of 32 threads, one per slot
    {
        int p = t >> 5, l = t & 31;
        int r = s_sel[p];
        if (r >= 0) {
            int tr = s_tgt[r];
            if (s_cnt[tr] < BOUNDARY) {          // anchor: class size <= 3
                for (int j = l; j < BB; j += 32)
                    if (j != r && s_tgt[j] == tr) {
                        int idx = atomicAdd(&s_np, 1);
                        s_pr[idx] = r; s_pj[idx] = j;
                    }
            }
        }
    }
    __syncthreads();

    // hinge terms: <= 16 pairs, all resident in wave 0
    float s = 0.f; int c = 0;
    if (t < s_np) {
        int r = s_pr[t], j = s_pj[t];
        const float4* xr = (const float4*)(x + r * DD);
        const float4* xj = (const float4*)(x + j * DD);
        float d0 = 0.f, d1 = 0.f, d2 = 0.f, d3 = 0.f;
        for (int cc = 0; cc < DD / 4; ++cc) {
            float4 a = xr[cc], b = xj[cc];
            d0 += a.x * b.x; d1 += a.y * b.y; d2 += a.z * b.z; d3 += a.w * b.w;
        }
        float dot = (d0 + d1) + (d2 + d3);
        float dsq = fmaxf((s_sq[r] + s_sq[j]) - 2.f * dot, 0.f);
        float dpos = (dsq == 0.f) ? 0.f : sqrtf(dsq);
        float tv = dpos - s_d[r] + 1.0f;         // d[r,j] - d[r,k] + margin
        if (tv > 0.f) { s = tv; c = (tv > 1e-7f) ? 1 : 0; }
    }

    if (wave == 0) {
        for (int off = 32; off > 0; off >>= 1) {
            s += __shfl_down(s, off);
            c += __shfl_down(c, off);
        }
        int isFinal = 0;
        if (lane == 0) {
            char* cell = cells + (size_t)(k & (NSHARD - 1)) * CELL_STRIDE;
            float*    cS = (float*)cell;
            int*      cC = (int*)(cell + 4);
            unsigned* dS = (unsigned*)(cell + 8);
            // init-from-poison (<= 8 contenders per address)
            atomicCAS((unsigned*)cS, POISON, 0u);
            atomicCAS((unsigned*)cC, POISON, 0u);
            atomicCAS(dS, POISON, 0u);
            if (s != 0.f) atomicAdd(cS, s);
            if (c != 0)   atomicAdd(cC, c);
            __threadfence();                         // release this block's adds
            unsigned prev = atomicAdd(dS, 1u);
            if (prev == (BB / NSHARD) - 1) {         // shard-last of 8
                __threadfence();                     // acquire shard + release onward
                atomicCAS(done2, POISON, 0u);        // <= 64 contenders
                unsigned p2 = atomicAdd(done2, 1u);
                if (p2 == NSHARD - 1) isFinal = 1;   // grid-last
            }
        }
        isFinal = __shfl(isFinal, 0);
        if (isFinal) {                               // all adds happen-before here
            __threadfence();                         // acquire
            char* cell = cells + (size_t)lane * CELL_STRIDE;
            float S = atomicAdd((float*)cell, 0.f);  // coherent atomic reads
            int   C = atomicAdd((int*)(cell + 4), 0);
            for (int off = 32; off > 0; off >>= 1) {
                S += __shfl_down(S, off);
                C += __shfl_down(C, off);
            }
            if (lane == 0) out[0] = S / ((float)C + 1e-7f);
        }
    }
}

extern "C" void kernel_launch(void* const* d_in, const int* in_sizes, int n_in,
                              void* d_out, int out_size, void* d_ws, size_t ws_size,
                              hipStream_t stream) {
    const float* x   = (const float*)d_in[0];
    const int*   tgt = (const int*)d_in[1];
    float* out = (float*)d_out;

    char*     cells = (char*)d_ws;
    unsigned* done2 = (unsigned*)((char*)d_ws + NSHARD * CELL_STRIDE);

    fused_kernel<<<BB, 256, 0, stream>>>(x, tgt, cells, done2, out);
}